// Round 11
// baseline (117.989 us; speedup 1.0000x reference)
//
#include <hip/hip_runtime.h>
#include <math.h>

#define NCC 80
#define TOPKK 13
#define BB 16
#define NAA 8400
#define NMX 64
#define NROW (BB * NMX)        // 1024
#define NBA  (BB * NAA)        // 134400
#define PDEPTH 13              // per-thread exact top-13
#define PSTR 15                // odd stride: conflict-free; slot 13 = sentinel
#define SENT 0x7fffffff
#define NZI (NBA + 2 * NROW)   // cnt | pos zero region, 136448 ints
#define NZI4 (NZI / 4)         // 34112
#define EPSF 1e-9f
#define IOUEPS 1e-7f
#define INV_PI2 0.4052847345693511f

__device__ __forceinline__ float ciou2(float gx1, float gy1, float gx2, float gy2,
                                       float gw, float gh, float gat,
                                       float px1, float py1, float px2, float py2,
                                       float pat)
{
    float w2 = px2 - px1, h2 = py2 - py1;
    float iw = fmaxf(fminf(gx2, px2) - fmaxf(gx1, px1), 0.f);
    float ih = fmaxf(fminf(gy2, py2) - fmaxf(gy1, py1), 0.f);
    float inter = iw * ih;
    float uni = gw * gh + w2 * h2 - inter + IOUEPS;
    float iou = inter / uni;
    float cw = fmaxf(gx2, px2) - fminf(gx1, px1);
    float ch = fmaxf(gy2, py2) - fminf(gy1, py1);
    float c2 = cw * cw + ch * ch + IOUEPS;
    float dx = px1 + px2 - gx1 - gx2;
    float dy = py1 + py2 - gy1 - gy2;
    float rho2 = (dx * dx + dy * dy) * 0.25f;
    float da = pat - gat;
    float v = INV_PI2 * da * da;
    float alpha = v / (v - iou + (1.f + IOUEPS));
    return iou - (rho2 / c2 + v * alpha);
}

// KZ: zero cnt | pos (contiguous).
__global__ __launch_bounds__(256) void kz_zero(int4* __restrict__ z)
{
    int i = blockIdx.x * 256 + threadIdx.x;
    if (i < NZI4) z[i] = make_int4(0, 0, 0, 0);
}

// KA: fused single-pass scan + top-13 per gt row.
// Each thread scans its 33 strided anchors with 4x-unrolled prefetch (MLP);
// in-gt anchors get CIoU+score immediately and a depth-13 sorted insert
// (exact: global top-13 is a subset of the union of per-thread top-13s).
// {0..12} injection keeps lax.top_k equivalence for the zero-metric tail.
// Merge: per-wave 13-round shfl tournament (sentinel-guarded), ONE barrier,
// wave 0 merges 52 candidates, scatters packed count|jsum into cnt.
__global__ __launch_bounds__(256) void ka_topk(
    const float* __restrict__ pd_scores,
    const float* __restrict__ pd_bboxes,
    const float* __restrict__ anc,
    const int*   __restrict__ gt_labels,
    const float* __restrict__ gt_bboxes,
    const float* __restrict__ mask_gt,
    int* __restrict__ cnt)
{
    const int row = blockIdx.x;
    if (mask_gt[row] <= 0.f) return;
    const int b = row >> 6, j = row & 63;
    const int tid = threadIdx.x;
    const int lane = tid & 63, wid = tid >> 6;

    const float4 g = reinterpret_cast<const float4*>(gt_bboxes)[row];
    const float gw = g.z - g.x, gh = g.w - g.y;
    const float gat = atanf(gw / gh);
    const int gl = gt_labels[row];
    const float* sc = pd_scores + (size_t)b * NAA * NCC + gl;
    const float4* pb = reinterpret_cast<const float4*>(pd_bboxes) + (size_t)b * NAA;
    const float2* ap2 = reinterpret_cast<const float2*>(anc);

    __shared__ float cV[64];
    __shared__ int   cI[64];
    __shared__ float Lv[256 * PSTR];
    __shared__ int   Li[256 * PSTR];

    float lv[PDEPTH]; int li[PDEPTH];
#pragma unroll
    for (int k = 0; k < PDEPTH; k++) { lv[k] = -1.f; li[k] = SENT; }

#define INSERT(AL, A)                                                            \
    if ((AL) > lv[PDEPTH - 1] || ((AL) == lv[PDEPTH - 1] && (A) < li[PDEPTH - 1])) { \
        lv[PDEPTH - 1] = (AL); li[PDEPTH - 1] = (A);                             \
        _Pragma("unroll")                                                        \
        for (int k = PDEPTH - 1; k > 0; --k) {                                   \
            if (lv[k] > lv[k - 1] || (lv[k] == lv[k - 1] && li[k] < li[k - 1])) {\
                float tv = lv[k]; lv[k] = lv[k - 1]; lv[k - 1] = tv;             \
                int ti = li[k]; li[k] = li[k - 1]; li[k - 1] = ti;               \
            } else break;                                                        \
        }                                                                        \
    }

#define PROC(AP, A)                                                              \
    {                                                                            \
        float din = fminf(fminf((AP).x - g.x, (AP).y - g.y),                     \
                          fminf(g.z - (AP).x, g.w - (AP).y));                    \
        if (din > EPSF) {                                                        \
            float4 p = pb[A];                                                    \
            float pat = atanf((p.z - p.x) / (p.w - p.y));                        \
            float c = ciou2(g.x, g.y, g.z, g.w, gw, gh, gat,                     \
                            p.x, p.y, p.z, p.w, pat);                            \
            float o = fmaxf(c, 0.f);                                             \
            float o2 = o * o;                                                    \
            float al = sc[(size_t)(A) * NCC] * (o2 * o2 * o2);                   \
            INSERT(al, A);                                                       \
        }                                                                        \
    }

    // injected candidates: a = tid < 13, only if NOT in-gt (else found in scan)
    if (tid < TOPKK) {
        float2 ap = ap2[tid];
        float din = fminf(fminf(ap.x - g.x, ap.y - g.y), fminf(g.z - ap.x, g.w - ap.y));
        if (!(din > EPSF)) { INSERT(0.f, tid); }
    }

    // main scan: 8 x (4 prefetched anchors) = 8192, then 208 tail
    for (int k = 0; k < 8; ++k) {
        const int a0 = tid + (k << 10);
        float2 A0 = ap2[a0];
        float2 A1 = ap2[a0 + 256];
        float2 A2 = ap2[a0 + 512];
        float2 A3 = ap2[a0 + 768];
        PROC(A0, a0);
        PROC(A1, a0 + 256);
        PROC(A2, a0 + 512);
        PROC(A3, a0 + 768);
    }
    {
        const int a = 8192 + tid;
        if (a < NAA) { float2 A = ap2[a]; PROC(A, a); }
    }
#undef PROC
#undef INSERT

    // spill lists (dynamic head index needs LDS); same-wave DS ops are ordered.
#pragma unroll
    for (int k = 0; k < PDEPTH; k++) { Lv[tid * PSTR + k] = lv[k]; Li[tid * PSTR + k] = li[k]; }
    Lv[tid * PSTR + PDEPTH] = -1.f;            // sentinel (exhausted head)
    Li[tid * PSTR + PDEPTH] = SENT;

    // ---- stage 1: per-wave 13-round shfl tournament (no barriers) ----
    int p = 0;
    float myv = -1.f; int myi = SENT;
    for (int r = 0; r < TOPKK; ++r) {
        float hv = Lv[tid * PSTR + p];
        int   hi = Li[tid * PSTR + p];
        float wv = hv; int wi = hi;
#pragma unroll
        for (int s = 1; s < 64; s <<= 1) {
            float ov = __shfl_xor(wv, s, 64);
            int   oi = __shfl_xor(wi, s, 64);
            if (ov > wv || (ov == wv && oi < wi)) { wv = ov; wi = oi; }
        }
        if (lane == r) { myv = wv; myi = wi; }
        if (hi == wi && wi != SENT) ++p;        // real win only -> p <= PDEPTH
    }
    if (lane < TOPKK) { cV[wid * TOPKK + lane] = myv; cI[wid * TOPKK + lane] = myi; }
    __syncthreads();                            // the ONLY block barrier

    // ---- stage 2: wave 0 merges 52 candidates, scatters winners ----
    if (wid == 0) {
        float v = (lane < 4 * TOPKK) ? cV[lane] : -2.f;
        int   i = (lane < 4 * TOPKK) ? cI[lane] : SENT;
        int fi = SENT;
        for (int r = 0; r < TOPKK; ++r) {
            float wv = v; int wi = i;
#pragma unroll
            for (int s = 1; s < 64; s <<= 1) {
                float ov = __shfl_xor(wv, s, 64);
                int   oi = __shfl_xor(wi, s, 64);
                if (ov > wv || (ov == wv && oi < wi)) { wv = ov; wi = oi; }
            }
            if (lane == r) fi = wi;
            if (i == wi && wi != SENT) v = -2.f;  // consume real winner only
        }
        if (lane < TOPKK && fi >= 0 && fi < NAA) {
            float2 ap = ap2[fi];
            float din = fminf(fminf(ap.x - g.x, ap.y - g.y), fminf(g.z - ap.x, g.w - ap.y));
            if (din > EPSF)
                atomicAdd(&cnt[(size_t)b * NAA + fi], 1 + (j << 8));
        }
    }
}

// K2: per-anchor multi-gt resolution + per-row pos maxima. Grid (33, B):
// each block serves one batch; gt boxes / masks / atan(gw/gh) staged in LDS.
__global__ __launch_bounds__(256) void k2_resolve(
    const float* __restrict__ pd_scores,
    const float* __restrict__ pd_bboxes,
    const float* __restrict__ anc,
    const int*   __restrict__ gt_labels,
    const float* __restrict__ gt_bboxes,
    const float* __restrict__ mask_gt,
    const int* __restrict__ cnt,
    int* __restrict__ tgt, int* __restrict__ fgm, float* __restrict__ alv,
    int* __restrict__ pos)
{
    const int tid = threadIdx.x;
    const int b = blockIdx.y;
    const int a = blockIdx.x * 256 + tid;

    __shared__ float4 glds[NMX];
    __shared__ float  mlds[NMX];
    __shared__ float  galds[NMX];
    if (tid < NMX) {
        float4 gg = reinterpret_cast<const float4*>(gt_bboxes)[b * NMX + tid];
        glds[tid] = gg;
        mlds[tid] = mask_gt[b * NMX + tid];
        galds[tid] = atanf((gg.z - gg.x) / (gg.w - gg.y));
    }
    __syncthreads();
    if (a >= NAA) return;

    const int id = b * NAA + a;
    const int v = cnt[id];
    const int fg = v & 0xff;
    int tj = 0, f = 0;
    float al = 0.f;
    if (fg > 0) {
        f = 1;
        float2 ap = reinterpret_cast<const float2*>(anc)[a];
        float4 p = reinterpret_cast<const float4*>(pd_bboxes)[id];
        float pat = atanf((p.z - p.x) / (p.w - p.y));
        if (fg == 1) {
            tj = v >> 8;
        } else {
            float bv = -1.f; int bj = 0;
            for (int jj = 0; jj < NMX; ++jj) {
                float4 g = glds[jj];
                float din = fminf(fminf(ap.x - g.x, ap.y - g.y), fminf(g.z - ap.x, g.w - ap.y));
                float ov = 0.f;
                if (din > EPSF && mlds[jj] > 0.f) {
                    float c = ciou2(g.x, g.y, g.z, g.w, g.z - g.x, g.w - g.y, galds[jj],
                                    p.x, p.y, p.z, p.w, pat);
                    ov = fmaxf(c, 0.f);
                }
                if (ov > bv) { bv = ov; bj = jj; }   // strict > == first-argmax
            }
            tj = bj;
        }
        float4 g = glds[tj];
        float din = fminf(fminf(ap.x - g.x, ap.y - g.y), fminf(g.z - ap.x, g.w - ap.y));
        if (din > EPSF && mlds[tj] > 0.f) {
            float c = ciou2(g.x, g.y, g.z, g.w, g.z - g.x, g.w - g.y, galds[tj],
                            p.x, p.y, p.z, p.w, pat);
            float ov = fmaxf(c, 0.f);
            int gl = gt_labels[b * NMX + tj];
            float s = pd_scores[(size_t)id * NCC + gl];
            float o2 = ov * ov;
            al = s * (o2 * o2 * o2);
            if (ov > 0.f)
                atomicMax((unsigned int*)&pos[NROW + b * NMX + tj], __float_as_uint(ov));
        }
        if (al > 0.f)
            atomicMax((unsigned int*)&pos[b * NMX + tj], __float_as_uint(al));
    }
    tgt[id] = tj; fgm[id] = f; alv[id] = al;
}

// K3: all outputs, fully written; score region via coalesced float4 stores.
__global__ __launch_bounds__(256) void k3_out(
    const int* __restrict__ gt_labels,
    const float* __restrict__ gt_bboxes,
    const int* __restrict__ tgt, const int* __restrict__ fgm,
    const float* __restrict__ alv, const int* __restrict__ pos,
    float* __restrict__ o_lab, float* __restrict__ o_box, float* __restrict__ o_sc,
    float* __restrict__ o_fg, float* __restrict__ o_ti)
{
    const int id0 = blockIdx.x * 256;
    const int tid = threadIdx.x;
    const int id = id0 + tid;
    const int b = id / NAA;
    const int tj = tgt[id];
    const int f = fgm[id];
    int lab = gt_labels[b * NMX + tj]; lab = lab < 0 ? 0 : lab;
    float4 gb = reinterpret_cast<const float4*>(gt_bboxes)[b * NMX + tj];
    o_lab[id] = (float)lab;
    reinterpret_cast<float4*>(o_box)[id] = gb;
    o_fg[id] = f ? 1.f : 0.f;
    o_ti[id] = (float)tj;
    float val = 0.f;
    if (f) {
        float pa = __uint_as_float((unsigned int)pos[b * NMX + tj]);
        float po = __uint_as_float((unsigned int)pos[NROW + b * NMX + tj]);
        val = (alv[id] * po) / (pa + EPSF);
    }
    __shared__ int   s_lab[256];
    __shared__ float s_val[256];
    s_lab[tid] = lab;
    s_val[tid] = val;
    __syncthreads();
    float4* dst = reinterpret_cast<float4*>(o_sc + (size_t)id0 * NCC);
    const int NV = 256 * NCC / 4;   // 5120 float4s per block
#pragma unroll 4
    for (int i = tid; i < NV; i += 256) {
        int aa = i / (NCC / 4);
        int c0 = (i - aa * (NCC / 4)) * 4;
        int la = s_lab[aa];
        float vv = s_val[aa];
        float4 w;
        w.x = (la == c0 + 0) ? vv : 0.f;
        w.y = (la == c0 + 1) ? vv : 0.f;
        w.z = (la == c0 + 2) ? vv : 0.f;
        w.w = (la == c0 + 3) ? vv : 0.f;
        dst[i] = w;
    }
}

extern "C" void kernel_launch(void* const* d_in, const int* in_sizes, int n_in,
                              void* d_out, int out_size, void* d_ws, size_t ws_size,
                              hipStream_t stream)
{
    const float* pd_scores = (const float*)d_in[0];
    const float* pd_bboxes = (const float*)d_in[1];
    const float* anc       = (const float*)d_in[2];
    // d_in[3] rfields: unused by the reference
    const int*   gt_labels = (const int*)d_in[4];
    const float* gt_bboxes = (const float*)d_in[5];
    const float* mask_gt   = (const float*)d_in[6];

    const size_t nba = (size_t)NBA;
    int* cnt  = (int*)d_ws;                 // NBA
    int* pos  = cnt + nba;                  // 2*NROW (pos_al | pos_ov)
    int* tgt  = pos + 2 * NROW;             // NBA
    int* fgm  = tgt + nba;                  // NBA
    float* alv = (float*)(fgm + nba);       // NBA

    float* out = (float*)d_out;
    float* o_lab = out;                 // (B,NA)
    float* o_box = out + nba;           // (B,NA,4)
    float* o_sc  = out + nba * 5;       // (B,NA,NC)
    float* o_fg  = out + nba * 85;      // (B,NA)
    float* o_ti  = out + nba * 86;      // (B,NA)

    kz_zero<<<(NZI4 + 255) / 256, 256, 0, stream>>>((int4*)d_ws);
    ka_topk<<<NROW, 256, 0, stream>>>(pd_scores, pd_bboxes, anc, gt_labels,
                                      gt_bboxes, mask_gt, cnt);
    k2_resolve<<<dim3((NAA + 255) / 256, BB), 256, 0, stream>>>(
        pd_scores, pd_bboxes, anc, gt_labels, gt_bboxes, mask_gt, cnt,
        tgt, fgm, alv, pos);
    const int nblk = NBA / 256;   // 525, exact
    k3_out<<<nblk, 256, 0, stream>>>(gt_labels, gt_bboxes, tgt, fgm, alv, pos,
                                     o_lab, o_box, o_sc, o_fg, o_ti);
}

// Round 12
// 75.453 us; speedup vs baseline: 1.5637x; 1.5637x over previous
//
#include <hip/hip_runtime.h>
#include <math.h>

#define NCC 80
#define TOPKK 13
#define BB 16
#define NAA 8400
#define NMX 64
#define NROW (BB * NMX)        // 1024
#define NBA  (BB * NAA)        // 134400
#define CHNK 4                 // anchor chunks per row
#define CHSZ 2100              // NAA / CHNK
#define SEGC 256               // per-wave segment capacity (E[hits]~10)
#define NCND (CHNK * 52)       // 208 candidates per row into merge
#define SENT 0x7fffffff
#define NZI (NBA + 2 * NROW)   // cnt | pos zero region
#define NZI4 (NZI / 4)
#define EPSF 1e-9f
#define IOUEPS 1e-7f
#define INV_PI2 0.4052847345693511f

__device__ __forceinline__ float ciou2(float gx1, float gy1, float gx2, float gy2,
                                       float gw, float gh, float gat,
                                       float px1, float py1, float px2, float py2,
                                       float pat)
{
    float w2 = px2 - px1, h2 = py2 - py1;
    float iw = fmaxf(fminf(gx2, px2) - fmaxf(gx1, px1), 0.f);
    float ih = fmaxf(fminf(gy2, py2) - fmaxf(gy1, py1), 0.f);
    float inter = iw * ih;
    float uni = gw * gh + w2 * h2 - inter + IOUEPS;
    float iou = inter / uni;
    float cw = fmaxf(gx2, px2) - fminf(gx1, px1);
    float ch = fmaxf(gy2, py2) - fminf(gy1, py1);
    float c2 = cw * cw + ch * ch + IOUEPS;
    float dx = px1 + px2 - gx1 - gx2;
    float dy = py1 + py2 - gy1 - gy2;
    float rho2 = (dx * dx + dy * dy) * 0.25f;
    float da = pat - gat;
    float v = INV_PI2 * da * da;
    float alpha = v / (v - iou + (1.f + IOUEPS));
    return iou - (rho2 / c2 + v * alpha);
}

// KZ: zero cnt | pos (contiguous).
__global__ __launch_bounds__(256) void kz_zero(int4* __restrict__ z)
{
    int i = blockIdx.x * 256 + threadIdx.x;
    if (i < NZI4) z[i] = make_int4(0, 0, 0, 0);
}

// KA: one block per (chunk, row). Register-compaction scan (no LDS atomics:
// per-wave private segment, position from running register count + ballot
// popc), then align_metric on the dense candidate list, per-thread depth-4
// register lists, per-wave 13-round shfl tournament -> 52 candidates/chunk
// written straight to global candV/candI. {0..12} injection in chunk 0 keeps
// exact lax.top_k equivalence. ONE barrier total.
__global__ __launch_bounds__(256) void ka_topk(
    const float* __restrict__ pd_scores,
    const float* __restrict__ pd_bboxes,
    const float* __restrict__ anc,
    const int*   __restrict__ gt_labels,
    const float* __restrict__ gt_bboxes,
    const float* __restrict__ mask_gt,
    float* __restrict__ candV, int* __restrict__ candI)
{
    const int chunk = blockIdx.x;
    const int row = blockIdx.y;
    if (mask_gt[row] <= 0.f) return;
    const int b = row >> 6;
    const int tid = threadIdx.x;
    const int lane = tid & 63, wid = tid >> 6;

    const float4 g = reinterpret_cast<const float4*>(gt_bboxes)[row];
    const float gw = g.z - g.x, gh = g.w - g.y;
    const float gat = atanf(gw / gh);
    const int gl = gt_labels[row];
    const float* sc = pd_scores + (size_t)b * NAA * NCC + gl;
    const float4* pb = reinterpret_cast<const float4*>(pd_bboxes) + (size_t)b * NAA;
    const float2* ap2 = reinterpret_cast<const float2*>(anc);

    __shared__ int seg[4][SEGC];
    __shared__ int wcnt[4];

    // ---- pass 1: per-wave register compaction (no LDS atomics) ----
    int wbase = 0;
    const int a0 = chunk * CHSZ;
    for (int a = a0 + tid; a < a0 + CHSZ; a += 256) {
        float2 ap = ap2[a];
        float din = fminf(fminf(ap.x - g.x, ap.y - g.y), fminf(g.z - ap.x, g.w - ap.y));
        bool take = din > EPSF;
        unsigned long long m = __ballot(take);
        if (take) {
            int pos = wbase + __popcll(m & ((1ull << lane) - 1ull));
            if (pos < SEGC) seg[wid][pos] = a;
        }
        wbase += __popcll(m);
    }
    if (lane == 0) wcnt[wid] = wbase > SEGC ? SEGC : wbase;
    __syncthreads();                            // the ONLY barrier

    const int n0 = wcnt[0], n1 = wcnt[1], n2 = wcnt[2], n3 = wcnt[3];
    const int c1 = n0, c2 = n0 + n1, c3 = n0 + n1 + n2;
    const int nc = c3 + n3;

    // ---- pass 2: dense align_metric, per-thread depth-4 register list ----
    float lv[4]; int li[4];
#pragma unroll
    for (int k = 0; k < 4; ++k) { lv[k] = -1.f; li[k] = SENT; }

#define INSERT(AL, A)                                                           \
    if ((AL) > lv[3] || ((AL) == lv[3] && (A) < li[3])) {                       \
        lv[3] = (AL); li[3] = (A);                                              \
        _Pragma("unroll")                                                       \
        for (int k = 3; k > 0; --k) {                                           \
            if (lv[k] > lv[k - 1] || (lv[k] == lv[k - 1] && li[k] < li[k - 1])) {\
                float tv = lv[k]; lv[k] = lv[k - 1]; lv[k - 1] = tv;            \
                int ti = li[k]; li[k] = li[k - 1]; li[k - 1] = ti;              \
            } else break;                                                       \
        }                                                                       \
    }

    // injected candidates (chunk 0 owns indices 0..12): only if NOT in-gt
    if (chunk == 0 && tid < TOPKK) {
        float2 ap = ap2[tid];
        float din = fminf(fminf(ap.x - g.x, ap.y - g.y), fminf(g.z - ap.x, g.w - ap.y));
        if (!(din > EPSF)) { INSERT(0.f, tid); }
    }

    for (int t = tid; t < nc; t += 256) {
        int w, idx;
        if (t < c1)      { w = 0; idx = t; }
        else if (t < c2) { w = 1; idx = t - c1; }
        else if (t < c3) { w = 2; idx = t - c2; }
        else             { w = 3; idx = t - c3; }
        int a = seg[w][idx];
        float4 p = pb[a];
        float pat = atanf((p.z - p.x) / (p.w - p.y));
        float c = ciou2(g.x, g.y, g.z, g.w, gw, gh, gat, p.x, p.y, p.z, p.w, pat);
        float o = fmaxf(c, 0.f);
        float o2 = o * o;
        float al = sc[(size_t)a * NCC] * (o2 * o2 * o2);
        INSERT(al, a);
    }
#undef INSERT

    // ---- per-wave 13-round tournament (registers only; select chain) ----
    int p = 0;
    float myv = -1.f; int myi = SENT;
    for (int r = 0; r < TOPKK; ++r) {
        float hv = lv[0]; int hi = li[0];
        if (p == 1)      { hv = lv[1]; hi = li[1]; }
        else if (p == 2) { hv = lv[2]; hi = li[2]; }
        else if (p == 3) { hv = lv[3]; hi = li[3]; }
        else if (p >= 4) { hv = -1.f;  hi = SENT; }
        float wv = hv; int wi = hi;
#pragma unroll
        for (int s = 1; s < 64; s <<= 1) {
            float ov = __shfl_xor(wv, s, 64);
            int   oi = __shfl_xor(wi, s, 64);
            if (ov > wv || (ov == wv && oi < wi)) { wv = ov; wi = oi; }
        }
        if (lane == r) { myv = wv; myi = wi; }
        if (hi == wi && wi != SENT) ++p;        // real win only
    }
    if (lane < TOPKK) {
        int o = row * NCND + chunk * 52 + wid * TOPKK + lane;
        candV[o] = myv; candI[o] = myi;
    }
}

// KM: one wave per row. Consume-tournament over 208 distinct candidates
// (4 chunks x 52), exact (value desc, index asc); din-filter; scatter
// packed count|jsum into cnt.
__global__ __launch_bounds__(256) void km_merge(
    const float* __restrict__ candV, const int* __restrict__ candI,
    const float* __restrict__ anc,
    const float* __restrict__ gt_bboxes,
    const float* __restrict__ mask_gt,
    int* __restrict__ cnt)
{
    const int tid = threadIdx.x;
    const int lane = tid & 63, wid = tid >> 6;
    const int row = blockIdx.x * 4 + wid;
    if (mask_gt[row] <= 0.f) return;
    const int b = row >> 6, j = row & 63;

    const float* cv = candV + (size_t)row * NCND;
    const int*   ci = candI + (size_t)row * NCND;
    float v0 = cv[lane],       v1 = cv[lane + 64], v2 = cv[lane + 128];
    int   i0 = ci[lane],       i1 = ci[lane + 64], i2 = ci[lane + 128];
    float v3 = (lane + 192 < NCND) ? cv[lane + 192] : -2.f;
    int   i3 = (lane + 192 < NCND) ? ci[lane + 192] : SENT;
    if (i0 == SENT) v0 = -2.f;
    if (i1 == SENT) v1 = -2.f;
    if (i2 == SENT) v2 = -2.f;
    if (i3 == SENT) v3 = -2.f;

    int fi = SENT;
    for (int r = 0; r < TOPKK; ++r) {
        float bv = v0; int bi = i0;
        if (v1 > bv || (v1 == bv && i1 < bi)) { bv = v1; bi = i1; }
        if (v2 > bv || (v2 == bv && i2 < bi)) { bv = v2; bi = i2; }
        if (v3 > bv || (v3 == bv && i3 < bi)) { bv = v3; bi = i3; }
        float wv = bv; int wi = bi;
#pragma unroll
        for (int s = 1; s < 64; s <<= 1) {
            float ov = __shfl_xor(wv, s, 64);
            int   oi = __shfl_xor(wi, s, 64);
            if (ov > wv || (ov == wv && oi < wi)) { wv = ov; wi = oi; }
        }
        if (lane == r) fi = wi;
        if (wi != SENT) {                       // consume real winner only
            if (i0 == wi) v0 = -2.f;
            if (i1 == wi) v1 = -2.f;
            if (i2 == wi) v2 = -2.f;
            if (i3 == wi) v3 = -2.f;
        }
    }
    if (lane < TOPKK && fi != SENT) {
        float4 g = reinterpret_cast<const float4*>(gt_bboxes)[row];
        float2 ap = reinterpret_cast<const float2*>(anc)[fi];
        float din = fminf(fminf(ap.x - g.x, ap.y - g.y), fminf(g.z - ap.x, g.w - ap.y));
        if (din > EPSF)
            atomicAdd(&cnt[(size_t)b * NAA + fi], 1 + (j << 8));
    }
}

// K2: per-anchor multi-gt resolution + per-row pos maxima (unchanged R10).
__global__ __launch_bounds__(256) void k2_resolve(
    const float* __restrict__ pd_scores,
    const float* __restrict__ pd_bboxes,
    const float* __restrict__ anc,
    const int*   __restrict__ gt_labels,
    const float* __restrict__ gt_bboxes,
    const float* __restrict__ mask_gt,
    const int* __restrict__ cnt,
    int* __restrict__ tgt, int* __restrict__ fgm, float* __restrict__ alv,
    int* __restrict__ pos)
{
    const int tid = threadIdx.x;
    const int b = blockIdx.y;
    const int a = blockIdx.x * 256 + tid;

    __shared__ float4 glds[NMX];
    __shared__ float  mlds[NMX];
    __shared__ float  galds[NMX];
    if (tid < NMX) {
        float4 gg = reinterpret_cast<const float4*>(gt_bboxes)[b * NMX + tid];
        glds[tid] = gg;
        mlds[tid] = mask_gt[b * NMX + tid];
        galds[tid] = atanf((gg.z - gg.x) / (gg.w - gg.y));
    }
    __syncthreads();
    if (a >= NAA) return;

    const int id = b * NAA + a;
    const int v = cnt[id];
    const int fg = v & 0xff;
    int tj = 0, f = 0;
    float al = 0.f;
    if (fg > 0) {
        f = 1;
        float2 ap = reinterpret_cast<const float2*>(anc)[a];
        float4 p = reinterpret_cast<const float4*>(pd_bboxes)[id];
        float pat = atanf((p.z - p.x) / (p.w - p.y));
        if (fg == 1) {
            tj = v >> 8;
        } else {
            float bv = -1.f; int bj = 0;
            for (int jj = 0; jj < NMX; ++jj) {
                float4 g = glds[jj];
                float din = fminf(fminf(ap.x - g.x, ap.y - g.y), fminf(g.z - ap.x, g.w - ap.y));
                float ov = 0.f;
                if (din > EPSF && mlds[jj] > 0.f) {
                    float c = ciou2(g.x, g.y, g.z, g.w, g.z - g.x, g.w - g.y, galds[jj],
                                    p.x, p.y, p.z, p.w, pat);
                    ov = fmaxf(c, 0.f);
                }
                if (ov > bv) { bv = ov; bj = jj; }   // strict > == first-argmax
            }
            tj = bj;
        }
        float4 g = glds[tj];
        float din = fminf(fminf(ap.x - g.x, ap.y - g.y), fminf(g.z - ap.x, g.w - ap.y));
        if (din > EPSF && mlds[tj] > 0.f) {
            float c = ciou2(g.x, g.y, g.z, g.w, g.z - g.x, g.w - g.y, galds[tj],
                            p.x, p.y, p.z, p.w, pat);
            float ov = fmaxf(c, 0.f);
            int gl = gt_labels[b * NMX + tj];
            float s = pd_scores[(size_t)id * NCC + gl];
            float o2 = ov * ov;
            al = s * (o2 * o2 * o2);
            if (ov > 0.f)
                atomicMax((unsigned int*)&pos[NROW + b * NMX + tj], __float_as_uint(ov));
        }
        if (al > 0.f)
            atomicMax((unsigned int*)&pos[b * NMX + tj], __float_as_uint(al));
    }
    tgt[id] = tj; fgm[id] = f; alv[id] = al;
}

// K3: all outputs, fully written (unchanged R10).
__global__ __launch_bounds__(256) void k3_out(
    const int* __restrict__ gt_labels,
    const float* __restrict__ gt_bboxes,
    const int* __restrict__ tgt, const int* __restrict__ fgm,
    const float* __restrict__ alv, const int* __restrict__ pos,
    float* __restrict__ o_lab, float* __restrict__ o_box, float* __restrict__ o_sc,
    float* __restrict__ o_fg, float* __restrict__ o_ti)
{
    const int id0 = blockIdx.x * 256;
    const int tid = threadIdx.x;
    const int id = id0 + tid;
    const int b = id / NAA;
    const int tj = tgt[id];
    const int f = fgm[id];
    int lab = gt_labels[b * NMX + tj]; lab = lab < 0 ? 0 : lab;
    float4 gb = reinterpret_cast<const float4*>(gt_bboxes)[b * NMX + tj];
    o_lab[id] = (float)lab;
    reinterpret_cast<float4*>(o_box)[id] = gb;
    o_fg[id] = f ? 1.f : 0.f;
    o_ti[id] = (float)tj;
    float val = 0.f;
    if (f) {
        float pa = __uint_as_float((unsigned int)pos[b * NMX + tj]);
        float po = __uint_as_float((unsigned int)pos[NROW + b * NMX + tj]);
        val = (alv[id] * po) / (pa + EPSF);
    }
    __shared__ int   s_lab[256];
    __shared__ float s_val[256];
    s_lab[tid] = lab;
    s_val[tid] = val;
    __syncthreads();
    float4* dst = reinterpret_cast<float4*>(o_sc + (size_t)id0 * NCC);
    const int NV = 256 * NCC / 4;   // 5120 float4s per block
#pragma unroll 4
    for (int i = tid; i < NV; i += 256) {
        int aa = i / (NCC / 4);
        int c0 = (i - aa * (NCC / 4)) * 4;
        int la = s_lab[aa];
        float vv = s_val[aa];
        float4 w;
        w.x = (la == c0 + 0) ? vv : 0.f;
        w.y = (la == c0 + 1) ? vv : 0.f;
        w.z = (la == c0 + 2) ? vv : 0.f;
        w.w = (la == c0 + 3) ? vv : 0.f;
        dst[i] = w;
    }
}

extern "C" void kernel_launch(void* const* d_in, const int* in_sizes, int n_in,
                              void* d_out, int out_size, void* d_ws, size_t ws_size,
                              hipStream_t stream)
{
    const float* pd_scores = (const float*)d_in[0];
    const float* pd_bboxes = (const float*)d_in[1];
    const float* anc       = (const float*)d_in[2];
    // d_in[3] rfields: unused by the reference
    const int*   gt_labels = (const int*)d_in[4];
    const float* gt_bboxes = (const float*)d_in[5];
    const float* mask_gt   = (const float*)d_in[6];

    const size_t nba = (size_t)NBA;
    int* cnt   = (int*)d_ws;                    // NBA
    int* pos   = cnt + nba;                     // 2*NROW
    float* candV = (float*)(pos + 2 * NROW);    // NROW*NCND
    int*   candI = (int*)(candV + (size_t)NROW * NCND);
    int* tgt   = candI + (size_t)NROW * NCND;   // NBA
    int* fgm   = tgt + nba;                     // NBA
    float* alv = (float*)(fgm + nba);           // NBA

    float* out = (float*)d_out;
    float* o_lab = out;                 // (B,NA)
    float* o_box = out + nba;           // (B,NA,4)
    float* o_sc  = out + nba * 5;       // (B,NA,NC)
    float* o_fg  = out + nba * 85;      // (B,NA)
    float* o_ti  = out + nba * 86;      // (B,NA)

    kz_zero<<<(NZI4 + 255) / 256, 256, 0, stream>>>((int4*)d_ws);
    ka_topk<<<dim3(CHNK, NROW), 256, 0, stream>>>(pd_scores, pd_bboxes, anc,
                                                  gt_labels, gt_bboxes, mask_gt,
                                                  candV, candI);
    km_merge<<<NROW / 4, 256, 0, stream>>>(candV, candI, anc, gt_bboxes,
                                           mask_gt, cnt);
    k2_resolve<<<dim3((NAA + 255) / 256, BB), 256, 0, stream>>>(
        pd_scores, pd_bboxes, anc, gt_labels, gt_bboxes, mask_gt, cnt,
        tgt, fgm, alv, pos);
    const int nblk = NBA / 256;   // 525, exact
    k3_out<<<nblk, 256, 0, stream>>>(gt_labels, gt_bboxes, tgt, fgm, alv, pos,
                                     o_lab, o_box, o_sc, o_fg, o_ti);
}

// Round 13
// 58.961 us; speedup vs baseline: 2.0011x; 1.2797x over previous
//
#include <hip/hip_runtime.h>
#include <math.h>

#define NCC 80
#define TOPKK 13
#define BB 16
#define NAA 8400
#define NMX 64
#define NROW (BB * NMX)        // 1024
#define NBA  (BB * NAA)        // 134400
#define SEGC 1024              // positive-candidate capacity (worst realistic ~650 in-gt)
#define PSTR 5                 // slow-path LDS list stride (depth 4 + sentinel)
#define SENT 0x7fffffff
#define NZI (NBA + 2 * NROW)   // cnt | pos zero region
#define NZI4 (NZI / 4)
#define EPSF 1e-9f
#define IOUEPS 1e-7f
#define INV_PI2 0.4052847345693511f

__device__ __forceinline__ float ciou_pos(float gx1, float gy1, float gx2, float gy2,
                                          float gw, float gh, float gat, float inter,
                                          float px1, float py1, float px2, float py2)
{
    float w2 = px2 - px1, h2 = py2 - py1;
    float uni = gw * gh + w2 * h2 - inter + IOUEPS;
    float iou = inter / uni;
    float cw = fmaxf(gx2, px2) - fminf(gx1, px1);
    float ch = fmaxf(gy2, py2) - fminf(gy1, py1);
    float c2 = cw * cw + ch * ch + IOUEPS;
    float dx = px1 + px2 - gx1 - gx2;
    float dy = py1 + py2 - gy1 - gy2;
    float rho2 = (dx * dx + dy * dy) * 0.25f;
    float da = atanf(w2 / h2) - gat;
    float v = INV_PI2 * da * da;
    float alpha = v / (v - iou + (1.f + IOUEPS));
    return iou - (rho2 / c2 + v * alpha);
}

__device__ __forceinline__ float ciou2(float gx1, float gy1, float gx2, float gy2,
                                       float gw, float gh, float gat,
                                       float px1, float py1, float px2, float py2,
                                       float pat)
{
    float w2 = px2 - px1, h2 = py2 - py1;
    float iw = fmaxf(fminf(gx2, px2) - fmaxf(gx1, px1), 0.f);
    float ih = fmaxf(fminf(gy2, py2) - fmaxf(gy1, py1), 0.f);
    float inter = iw * ih;
    float uni = gw * gh + w2 * h2 - inter + IOUEPS;
    float iou = inter / uni;
    float cw = fmaxf(gx2, px2) - fminf(gx1, px1);
    float ch = fmaxf(gy2, py2) - fminf(gy1, py1);
    float c2 = cw * cw + ch * ch + IOUEPS;
    float dx = px1 + px2 - gx1 - gx2;
    float dy = py1 + py2 - gy1 - gy2;
    float rho2 = (dx * dx + dy * dy) * 0.25f;
    float da = pat - gat;
    float v = INV_PI2 * da * da;
    float alpha = v / (v - iou + (1.f + IOUEPS));
    return iou - (rho2 / c2 + v * alpha);
}

// KZ: zero cnt | pos (contiguous).
__global__ __launch_bounds__(256) void kz_zero(int4* __restrict__ z)
{
    int i = blockIdx.x * 256 + threadIdx.x;
    if (i < NZI4) z[i] = make_int4(0, 0, 0, 0);
}

// KA: one block per (b,j) row. Sparsity-exact top-13:
//   align>0 requires pred-box overlap with gt (inter>0), ~3% of in-gt anchors.
//   Top-13 of (val desc, idx asc) over the full row == all positives (if
//   n_pos<=13) + the (13-n_pos) smallest NON-POSITIVE indices, which always
//   lie in {0..12} (every idx<13 is a candidate with val 0 unless positive).
//   Fast path: no selection at all — scatter positives + ranked {0..12}
//   prefix passing din. Slow path (n_pos>13, rare): exact (val,idx) merge
//   over the compacted positives only.
__global__ __launch_bounds__(256, 4) void ka_topk(
    const float* __restrict__ pd_scores,
    const float* __restrict__ pd_bboxes,
    const float* __restrict__ anc,
    const int*   __restrict__ gt_labels,
    const float* __restrict__ gt_bboxes,
    const float* __restrict__ mask_gt,
    int* __restrict__ cnt)
{
    const int row = blockIdx.x;
    if (mask_gt[row] <= 0.f) return;
    const int b = row >> 6, j = row & 63;
    const int tid = threadIdx.x;
    const int lane = tid & 63, wid = tid >> 6;

    const float4 g = reinterpret_cast<const float4*>(gt_bboxes)[row];
    const float gw = g.z - g.x, gh = g.w - g.y;
    const float gat = atanf(gw / gh);
    const int gl = gt_labels[row];
    const float* sc = pd_scores + (size_t)b * NAA * NCC + gl;
    const float4* pb = reinterpret_cast<const float4*>(pd_bboxes) + (size_t)b * NAA;
    const float2* ap2 = reinterpret_cast<const float2*>(anc);

    __shared__ float posV[SEGC];
    __shared__ int   posI[SEGC];
    __shared__ int   npos;
    __shared__ unsigned int pmask;   // positive indices among {0..12}
    if (tid == 0) { npos = 0; pmask = 0u; }
    __syncthreads();

    // ---- scan: only pred-overlapping in-gt anchors are positive ----
    for (int a = tid; a < NAA; a += 256) {
        float2 ap = ap2[a];
        float din = fminf(fminf(ap.x - g.x, ap.y - g.y), fminf(g.z - ap.x, g.w - ap.y));
        bool cand = false;
        float al = 0.f;
        if (din > EPSF) {
            float4 p = pb[a];
            float iw = fminf(g.z, p.z) - fmaxf(g.x, p.x);
            float ih = fminf(g.w, p.w) - fmaxf(g.y, p.y);
            if (iw > 0.f && ih > 0.f) {
                float c = ciou_pos(g.x, g.y, g.z, g.w, gw, gh, gat, iw * ih,
                                   p.x, p.y, p.z, p.w);
                float o = fmaxf(c, 0.f);
                float o2 = o * o;
                al = sc[(size_t)a * NCC] * (o2 * o2 * o2);
                cand = al > 0.f;
            }
        }
        unsigned long long m = __ballot(cand);
        if (m) {
            int base = 0;
            int wc = __popcll(m);
            if (lane == 0) base = atomicAdd(&npos, wc);
            base = __shfl(base, 0, 64);
            if (cand) {
                int p = base + __popcll(m & ((1ull << lane) - 1ull));
                if (p < SEGC) { posV[p] = al; posI[p] = a; }
                if (a < TOPKK) atomicOr(&pmask, 1u << a);
            }
        }
    }
    __syncthreads();
    int n = npos; if (n > SEGC) n = SEGC;

    if (n <= TOPKK) {
        // ---- fast path: everyone wins; fill with smallest non-positive idx ----
        if (tid < n)
            atomicAdd(&cnt[(size_t)b * NAA + posI[tid]], 1 + (j << 8));
        if (tid < TOPKK) {
            unsigned int bits = (~pmask) & 0x1fffu;
            if ((bits >> tid) & 1u) {
                int rank = __popc(bits & ((1u << tid) - 1u));
                if (rank < TOPKK - n) {
                    float2 ap = ap2[tid];
                    float din = fminf(fminf(ap.x - g.x, ap.y - g.y),
                                      fminf(g.z - ap.x, g.w - ap.y));
                    if (din > EPSF)
                        atomicAdd(&cnt[(size_t)b * NAA + tid], 1 + (j << 8));
                }
            }
        }
        return;
    }

    // ---- slow path (rare): exact top-13 of the positive list ----
    {
        __shared__ float cV[64];
        __shared__ int   cI[64];
        __shared__ float Lv[256 * PSTR];
        __shared__ int   Li[256 * PSTR];

        float lv[4]; int li[4];
#pragma unroll
        for (int k = 0; k < 4; ++k) { lv[k] = -1.f; li[k] = SENT; }
        for (int t = tid; t < n; t += 256) {
            float al = posV[t]; int a = posI[t];
            if (al > lv[3] || (al == lv[3] && a < li[3])) {
                lv[3] = al; li[3] = a;
#pragma unroll
                for (int k = 3; k > 0; --k) {
                    if (lv[k] > lv[k - 1] || (lv[k] == lv[k - 1] && li[k] < li[k - 1])) {
                        float tv = lv[k]; lv[k] = lv[k - 1]; lv[k - 1] = tv;
                        int ti = li[k]; li[k] = li[k - 1]; li[k - 1] = ti;
                    } else break;
                }
            }
        }
#pragma unroll
        for (int k = 0; k < 4; ++k) { Lv[tid * PSTR + k] = lv[k]; Li[tid * PSTR + k] = li[k]; }
        Lv[tid * PSTR + 4] = -1.f;
        Li[tid * PSTR + 4] = SENT;

        int p = 0;
        float myv = -1.f; int myi = SENT;
        for (int r = 0; r < TOPKK; ++r) {
            float hv = Lv[tid * PSTR + p];
            int   hi = Li[tid * PSTR + p];
            float wv = hv; int wi = hi;
#pragma unroll
            for (int s = 1; s < 64; s <<= 1) {
                float ov = __shfl_xor(wv, s, 64);
                int   oi = __shfl_xor(wi, s, 64);
                if (ov > wv || (ov == wv && oi < wi)) { wv = ov; wi = oi; }
            }
            if (lane == r) { myv = wv; myi = wi; }
            if (hi == wi && wi != SENT) ++p;
        }
        if (lane < TOPKK) { cV[wid * TOPKK + lane] = myv; cI[wid * TOPKK + lane] = myi; }
        __syncthreads();

        if (wid == 0) {
            float v = (lane < 4 * TOPKK) ? cV[lane] : -2.f;
            int   i = (lane < 4 * TOPKK) ? cI[lane] : SENT;
            int fi = SENT;
            for (int r = 0; r < TOPKK; ++r) {
                float wv = v; int wi = i;
#pragma unroll
                for (int s = 1; s < 64; s <<= 1) {
                    float ov = __shfl_xor(wv, s, 64);
                    int   oi = __shfl_xor(wi, s, 64);
                    if (ov > wv || (ov == wv && oi < wi)) { wv = ov; wi = oi; }
                }
                if (lane == r) fi = wi;
                if (i == wi && wi != SENT) v = -2.f;
            }
            if (lane < TOPKK && fi != SENT)
                atomicAdd(&cnt[(size_t)b * NAA + fi], 1 + (j << 8));
        }
    }
}

// K2: per-anchor multi-gt resolution + per-row pos maxima (unchanged R10).
__global__ __launch_bounds__(256) void k2_resolve(
    const float* __restrict__ pd_scores,
    const float* __restrict__ pd_bboxes,
    const float* __restrict__ anc,
    const int*   __restrict__ gt_labels,
    const float* __restrict__ gt_bboxes,
    const float* __restrict__ mask_gt,
    const int* __restrict__ cnt,
    int* __restrict__ tgt, int* __restrict__ fgm, float* __restrict__ alv,
    int* __restrict__ pos)
{
    const int tid = threadIdx.x;
    const int b = blockIdx.y;
    const int a = blockIdx.x * 256 + tid;

    __shared__ float4 glds[NMX];
    __shared__ float  mlds[NMX];
    __shared__ float  galds[NMX];
    if (tid < NMX) {
        float4 gg = reinterpret_cast<const float4*>(gt_bboxes)[b * NMX + tid];
        glds[tid] = gg;
        mlds[tid] = mask_gt[b * NMX + tid];
        galds[tid] = atanf((gg.z - gg.x) / (gg.w - gg.y));
    }
    __syncthreads();
    if (a >= NAA) return;

    const int id = b * NAA + a;
    const int v = cnt[id];
    const int fg = v & 0xff;
    int tj = 0, f = 0;
    float al = 0.f;
    if (fg > 0) {
        f = 1;
        float2 ap = reinterpret_cast<const float2*>(anc)[a];
        float4 p = reinterpret_cast<const float4*>(pd_bboxes)[id];
        float pat = atanf((p.z - p.x) / (p.w - p.y));
        if (fg == 1) {
            tj = v >> 8;
        } else {
            float bv = -1.f; int bj = 0;
            for (int jj = 0; jj < NMX; ++jj) {
                float4 g = glds[jj];
                float din = fminf(fminf(ap.x - g.x, ap.y - g.y), fminf(g.z - ap.x, g.w - ap.y));
                float ov = 0.f;
                if (din > EPSF && mlds[jj] > 0.f) {
                    float c = ciou2(g.x, g.y, g.z, g.w, g.z - g.x, g.w - g.y, galds[jj],
                                    p.x, p.y, p.z, p.w, pat);
                    ov = fmaxf(c, 0.f);
                }
                if (ov > bv) { bv = ov; bj = jj; }   // strict > == first-argmax
            }
            tj = bj;
        }
        float4 g = glds[tj];
        float din = fminf(fminf(ap.x - g.x, ap.y - g.y), fminf(g.z - ap.x, g.w - ap.y));
        if (din > EPSF && mlds[tj] > 0.f) {
            float c = ciou2(g.x, g.y, g.z, g.w, g.z - g.x, g.w - g.y, galds[tj],
                            p.x, p.y, p.z, p.w, pat);
            float ov = fmaxf(c, 0.f);
            int gl = gt_labels[b * NMX + tj];
            float s = pd_scores[(size_t)id * NCC + gl];
            float o2 = ov * ov;
            al = s * (o2 * o2 * o2);
            if (ov > 0.f)
                atomicMax((unsigned int*)&pos[NROW + b * NMX + tj], __float_as_uint(ov));
        }
        if (al > 0.f)
            atomicMax((unsigned int*)&pos[b * NMX + tj], __float_as_uint(al));
    }
    tgt[id] = tj; fgm[id] = f; alv[id] = al;
}

// K3: all outputs, fully written (unchanged R10).
__global__ __launch_bounds__(256) void k3_out(
    const int* __restrict__ gt_labels,
    const float* __restrict__ gt_bboxes,
    const int* __restrict__ tgt, const int* __restrict__ fgm,
    const float* __restrict__ alv, const int* __restrict__ pos,
    float* __restrict__ o_lab, float* __restrict__ o_box, float* __restrict__ o_sc,
    float* __restrict__ o_fg, float* __restrict__ o_ti)
{
    const int id0 = blockIdx.x * 256;
    const int tid = threadIdx.x;
    const int id = id0 + tid;
    const int b = id / NAA;
    const int tj = tgt[id];
    const int f = fgm[id];
    int lab = gt_labels[b * NMX + tj]; lab = lab < 0 ? 0 : lab;
    float4 gb = reinterpret_cast<const float4*>(gt_bboxes)[b * NMX + tj];
    o_lab[id] = (float)lab;
    reinterpret_cast<float4*>(o_box)[id] = gb;
    o_fg[id] = f ? 1.f : 0.f;
    o_ti[id] = (float)tj;
    float val = 0.f;
    if (f) {
        float pa = __uint_as_float((unsigned int)pos[b * NMX + tj]);
        float po = __uint_as_float((unsigned int)pos[NROW + b * NMX + tj]);
        val = (alv[id] * po) / (pa + EPSF);
    }
    __shared__ int   s_lab[256];
    __shared__ float s_val[256];
    s_lab[tid] = lab;
    s_val[tid] = val;
    __syncthreads();
    float4* dst = reinterpret_cast<float4*>(o_sc + (size_t)id0 * NCC);
    const int NV = 256 * NCC / 4;   // 5120 float4s per block
#pragma unroll 4
    for (int i = tid; i < NV; i += 256) {
        int aa = i / (NCC / 4);
        int c0 = (i - aa * (NCC / 4)) * 4;
        int la = s_lab[aa];
        float vv = s_val[aa];
        float4 w;
        w.x = (la == c0 + 0) ? vv : 0.f;
        w.y = (la == c0 + 1) ? vv : 0.f;
        w.z = (la == c0 + 2) ? vv : 0.f;
        w.w = (la == c0 + 3) ? vv : 0.f;
        dst[i] = w;
    }
}

extern "C" void kernel_launch(void* const* d_in, const int* in_sizes, int n_in,
                              void* d_out, int out_size, void* d_ws, size_t ws_size,
                              hipStream_t stream)
{
    const float* pd_scores = (const float*)d_in[0];
    const float* pd_bboxes = (const float*)d_in[1];
    const float* anc       = (const float*)d_in[2];
    // d_in[3] rfields: unused by the reference
    const int*   gt_labels = (const int*)d_in[4];
    const float* gt_bboxes = (const float*)d_in[5];
    const float* mask_gt   = (const float*)d_in[6];

    const size_t nba = (size_t)NBA;
    int* cnt  = (int*)d_ws;                 // NBA
    int* pos  = cnt + nba;                  // 2*NROW (pos_al | pos_ov)
    int* tgt  = pos + 2 * NROW;             // NBA
    int* fgm  = tgt + nba;                  // NBA
    float* alv = (float*)(fgm + nba);       // NBA

    float* out = (float*)d_out;
    float* o_lab = out;                 // (B,NA)
    float* o_box = out + nba;           // (B,NA,4)
    float* o_sc  = out + nba * 5;       // (B,NA,NC)
    float* o_fg  = out + nba * 85;      // (B,NA)
    float* o_ti  = out + nba * 86;      // (B,NA)

    kz_zero<<<(NZI4 + 255) / 256, 256, 0, stream>>>((int4*)d_ws);
    ka_topk<<<NROW, 256, 0, stream>>>(pd_scores, pd_bboxes, anc, gt_labels,
                                      gt_bboxes, mask_gt, cnt);
    k2_resolve<<<dim3((NAA + 255) / 256, BB), 256, 0, stream>>>(
        pd_scores, pd_bboxes, anc, gt_labels, gt_bboxes, mask_gt, cnt,
        tgt, fgm, alv, pos);
    const int nblk = NBA / 256;   // 525, exact
    k3_out<<<nblk, 256, 0, stream>>>(gt_labels, gt_bboxes, tgt, fgm, alv, pos,
                                     o_lab, o_box, o_sc, o_fg, o_ti);
}

// Round 14
// 50.869 us; speedup vs baseline: 2.3194x; 1.1591x over previous
//
#include <hip/hip_runtime.h>
#include <math.h>

#define NCC 80
#define TOPKK 13
#define BB 16
#define NAA 8400
#define NMX 64
#define NROW (BB * NMX)        // 1024
#define NBA  (BB * NAA)        // 134400
#define RCAP 1024              // per-row positive capacity (worst ~660 in-gt)
#define RPAD 16                // rcount: one counter per 64B line
#define PSTR 14                // kb slow-path LDS stride (13 + sentinel)
#define SENT 0x7fffffff
#define EPSF 1e-9f
#define IOUEPS 1e-7f
#define INV_PI2 0.4052847345693511f

__device__ __forceinline__ float ciou_pos(float gx1, float gy1, float gx2, float gy2,
                                          float gw, float gh, float gat, float inter,
                                          float px1, float py1, float px2, float py2)
{
    float w2 = px2 - px1, h2 = py2 - py1;
    float uni = gw * gh + w2 * h2 - inter + IOUEPS;
    float iou = inter / uni;
    float cw = fmaxf(gx2, px2) - fminf(gx1, px1);
    float ch = fmaxf(gy2, py2) - fminf(gy1, py1);
    float c2 = cw * cw + ch * ch + IOUEPS;
    float dx = px1 + px2 - gx1 - gx2;
    float dy = py1 + py2 - gy1 - gy2;
    float rho2 = (dx * dx + dy * dy) * 0.25f;
    float da = atanf(w2 / h2) - gat;
    float v = INV_PI2 * da * da;
    float alpha = v / (v - iou + (1.f + IOUEPS));
    return iou - (rho2 / c2 + v * alpha);
}

__device__ __forceinline__ float ciou2(float gx1, float gy1, float gx2, float gy2,
                                       float gw, float gh, float gat,
                                       float px1, float py1, float px2, float py2,
                                       float pat)
{
    float w2 = px2 - px1, h2 = py2 - py1;
    float iw = fmaxf(fminf(gx2, px2) - fmaxf(gx1, px1), 0.f);
    float ih = fmaxf(fminf(gy2, py2) - fmaxf(gy1, py1), 0.f);
    float inter = iw * ih;
    float uni = gw * gh + w2 * h2 - inter + IOUEPS;
    float iou = inter / uni;
    float cw = fmaxf(gx2, px2) - fminf(gx1, px1);
    float ch = fmaxf(gy2, py2) - fminf(gy1, py1);
    float c2 = cw * cw + ch * ch + IOUEPS;
    float dx = px1 + px2 - gx1 - gx2;
    float dy = py1 + py2 - gy1 - gy2;
    float rho2 = (dx * dx + dy * dy) * 0.25f;
    float da = pat - gat;
    float v = INV_PI2 * da * da;
    float alpha = v / (v - iou + (1.f + IOUEPS));
    return iou - (rho2 / c2 + v * alpha);
}

// KZ: zero padded rcount (the one array KP atomically increments).
__global__ __launch_bounds__(256) void kz_zero(int* __restrict__ rcount)
{
    int i = blockIdx.x * 256 + threadIdx.x;
    if (i < NROW * RPAD) rcount[i] = 0;
}

// KP: anchor-major positivity scan. One thread per (b, anchor): coalesced
// ap+pb load, then 64 LDS gt rows tested with din + pred-overlap (~15 ops).
// Only true positives (al>0, ~6/row) compute CIoU+score and append (val,idx)
// to per-row lists (ballot-aggregated, line-padded counters). Also zeroes
// cnt and pos inline (consumed only by later kernels).
__global__ __launch_bounds__(256) void kp_scan(
    const float* __restrict__ pd_scores,
    const float* __restrict__ pd_bboxes,
    const float* __restrict__ anc,
    const int*   __restrict__ gt_labels,
    const float* __restrict__ gt_bboxes,
    const float* __restrict__ mask_gt,
    int* __restrict__ cnt, int* __restrict__ pos,
    int* __restrict__ rcount, float* __restrict__ rV, int* __restrict__ rI)
{
    const int tid = threadIdx.x;
    const int lane = tid & 63;
    const int b = blockIdx.y;
    const int a = blockIdx.x * 256 + tid;
    const bool valid = a < NAA;

    __shared__ float4 glds[NMX];
    __shared__ float  mlds[NMX];
    __shared__ float  galds[NMX];
    __shared__ int    gllds[NMX];
    if (tid < NMX) {
        float4 gg = reinterpret_cast<const float4*>(gt_bboxes)[b * NMX + tid];
        glds[tid] = gg;
        mlds[tid] = mask_gt[b * NMX + tid];
        galds[tid] = atanf((gg.z - gg.x) / (gg.w - gg.y));
        gllds[tid] = gt_labels[b * NMX + tid];
    }
    if (b == 0 && blockIdx.x < 8) pos[blockIdx.x * 256 + tid] = 0;
    __syncthreads();

    float2 ap = valid ? reinterpret_cast<const float2*>(anc)[a]
                      : make_float2(-1e9f, -1e9f);
    float4 p  = valid ? reinterpret_cast<const float4*>(pd_bboxes)[(size_t)b * NAA + a]
                      : make_float4(0.f, 0.f, 0.f, 0.f);
    if (valid) cnt[b * NAA + a] = 0;
    const float* scb = pd_scores + ((size_t)b * NAA + a) * NCC;

    for (int j = 0; j < NMX; ++j) {
        float4 g = glds[j];
        float din = fminf(fminf(ap.x - g.x, ap.y - g.y), fminf(g.z - ap.x, g.w - ap.y));
        bool cand = false;
        float al = 0.f;
        if (din > EPSF && mlds[j] > 0.f) {
            float iw = fminf(g.z, p.z) - fmaxf(g.x, p.x);
            float ih = fminf(g.w, p.w) - fmaxf(g.y, p.y);
            if (iw > 0.f && ih > 0.f) {
                float c = ciou_pos(g.x, g.y, g.z, g.w, g.z - g.x, g.w - g.y,
                                   galds[j], iw * ih, p.x, p.y, p.z, p.w);
                float o = fmaxf(c, 0.f);
                float o2 = o * o;
                al = scb[gllds[j]] * (o2 * o2 * o2);
                cand = al > 0.f;
            }
        }
        unsigned long long m = __ballot(cand);
        if (m) {
            const int row = b * NMX + j;
            int base = 0;
            int wc = __popcll(m);
            if (lane == 0) base = atomicAdd(&rcount[row * RPAD], wc);
            base = __shfl(base, 0, 64);
            if (cand) {
                int pp = base + __popcll(m & ((1ull << lane) - 1ull));
                if (pp < RCAP) {
                    rV[(size_t)row * RCAP + pp] = al;
                    rI[(size_t)row * RCAP + pp] = a;
                }
            }
        }
    }
}

// KB: per-row finalize, one wave per row (4 rows/block).
// n<=13: all positives win + (13-n) ranked din-filtered fillers from {0..12}
//        (exact: non-positives rank by index; fillers provably lie in {0..12}).
// n>13 (rare): per-lane depth-13 lists + 13-round sentinel-guarded wave
//        tournament, exact (val desc, idx asc); winners scatter directly
//        (positives are pre-din-filtered).
__global__ __launch_bounds__(256) void kb_fin(
    const float* __restrict__ anc,
    const float* __restrict__ gt_bboxes,
    const float* __restrict__ mask_gt,
    const int* __restrict__ rcount,
    const float* __restrict__ rV, const int* __restrict__ rI,
    int* __restrict__ cnt)
{
    const int tid = threadIdx.x;
    const int lane = tid & 63, wid = tid >> 6;
    const int row = blockIdx.x * 4 + wid;
    const bool active = row < NROW && mask_gt[row] > 0.f;

    __shared__ float Lv[256 * PSTR];
    __shared__ int   Li[256 * PSTR];

    if (active) {
        const int b = row >> 6, j = row & 63;
        int n = rcount[row * RPAD]; if (n > RCAP) n = RCAP;

        if (n <= TOPKK) {
            unsigned int pm = 0;
            if (lane < n) {
                int a = rI[(size_t)row * RCAP + lane];
                atomicAdd(&cnt[(size_t)b * NAA + a], 1 + (j << 8));
                if (a < TOPKK) pm = 1u << a;
            }
#pragma unroll
            for (int s = 1; s < 64; s <<= 1) pm |= __shfl_xor(pm, s, 64);
            if (lane < TOPKK) {
                unsigned int bits = (~pm) & 0x1fffu;
                if ((bits >> lane) & 1u) {
                    int rank = __popc(bits & ((1u << lane) - 1u));
                    if (rank < TOPKK - n) {
                        float4 g = reinterpret_cast<const float4*>(gt_bboxes)[row];
                        float2 ap = reinterpret_cast<const float2*>(anc)[lane];
                        float din = fminf(fminf(ap.x - g.x, ap.y - g.y),
                                          fminf(g.z - ap.x, g.w - ap.y));
                        if (din > EPSF)
                            atomicAdd(&cnt[(size_t)b * NAA + lane], 1 + (j << 8));
                    }
                }
            }
        } else {
            // slow path: exact top-13 of the positive list
            float lv[TOPKK]; int li[TOPKK];
#pragma unroll
            for (int k = 0; k < TOPKK; ++k) { lv[k] = -1.f; li[k] = SENT; }
            for (int t = lane; t < n; t += 64) {
                float al = rV[(size_t)row * RCAP + t];
                int a = rI[(size_t)row * RCAP + t];
                if (al > lv[TOPKK - 1] || (al == lv[TOPKK - 1] && a < li[TOPKK - 1])) {
                    lv[TOPKK - 1] = al; li[TOPKK - 1] = a;
#pragma unroll
                    for (int k = TOPKK - 1; k > 0; --k) {
                        if (lv[k] > lv[k - 1] || (lv[k] == lv[k - 1] && li[k] < li[k - 1])) {
                            float tv = lv[k]; lv[k] = lv[k - 1]; lv[k - 1] = tv;
                            int ti = li[k]; li[k] = li[k - 1]; li[k - 1] = ti;
                        } else break;
                    }
                }
            }
#pragma unroll
            for (int k = 0; k < TOPKK; ++k) { Lv[tid * PSTR + k] = lv[k]; Li[tid * PSTR + k] = li[k]; }
            Lv[tid * PSTR + TOPKK] = -1.f;     // sentinel
            Li[tid * PSTR + TOPKK] = SENT;

            int p = 0;
            int myi = SENT;
            for (int r = 0; r < TOPKK; ++r) {
                float hv = Lv[tid * PSTR + p];
                int   hi = Li[tid * PSTR + p];
                float wv = hv; int wi = hi;
#pragma unroll
                for (int s = 1; s < 64; s <<= 1) {
                    float ov = __shfl_xor(wv, s, 64);
                    int   oi = __shfl_xor(wi, s, 64);
                    if (ov > wv || (ov == wv && oi < wi)) { wv = ov; wi = oi; }
                }
                if (lane == r) myi = wi;
                if (hi == wi && wi != SENT) ++p;
            }
            if (lane < TOPKK && myi != SENT)
                atomicAdd(&cnt[(size_t)b * NAA + myi], 1 + (j << 8));
        }
    }
}

// K2: per-anchor multi-gt resolution + per-row pos maxima (unchanged).
__global__ __launch_bounds__(256) void k2_resolve(
    const float* __restrict__ pd_scores,
    const float* __restrict__ pd_bboxes,
    const float* __restrict__ anc,
    const int*   __restrict__ gt_labels,
    const float* __restrict__ gt_bboxes,
    const float* __restrict__ mask_gt,
    const int* __restrict__ cnt,
    int* __restrict__ tgt, int* __restrict__ fgm, float* __restrict__ alv,
    int* __restrict__ pos)
{
    const int tid = threadIdx.x;
    const int b = blockIdx.y;
    const int a = blockIdx.x * 256 + tid;

    __shared__ float4 glds[NMX];
    __shared__ float  mlds[NMX];
    __shared__ float  galds[NMX];
    if (tid < NMX) {
        float4 gg = reinterpret_cast<const float4*>(gt_bboxes)[b * NMX + tid];
        glds[tid] = gg;
        mlds[tid] = mask_gt[b * NMX + tid];
        galds[tid] = atanf((gg.z - gg.x) / (gg.w - gg.y));
    }
    __syncthreads();
    if (a >= NAA) return;

    const int id = b * NAA + a;
    const int v = cnt[id];
    const int fg = v & 0xff;
    int tj = 0, f = 0;
    float al = 0.f;
    if (fg > 0) {
        f = 1;
        float2 ap = reinterpret_cast<const float2*>(anc)[a];
        float4 p = reinterpret_cast<const float4*>(pd_bboxes)[id];
        float pat = atanf((p.z - p.x) / (p.w - p.y));
        if (fg == 1) {
            tj = v >> 8;
        } else {
            float bv = -1.f; int bj = 0;
            for (int jj = 0; jj < NMX; ++jj) {
                float4 g = glds[jj];
                float din = fminf(fminf(ap.x - g.x, ap.y - g.y), fminf(g.z - ap.x, g.w - ap.y));
                float ov = 0.f;
                if (din > EPSF && mlds[jj] > 0.f) {
                    float c = ciou2(g.x, g.y, g.z, g.w, g.z - g.x, g.w - g.y, galds[jj],
                                    p.x, p.y, p.z, p.w, pat);
                    ov = fmaxf(c, 0.f);
                }
                if (ov > bv) { bv = ov; bj = jj; }   // strict > == first-argmax
            }
            tj = bj;
        }
        float4 g = glds[tj];
        float din = fminf(fminf(ap.x - g.x, ap.y - g.y), fminf(g.z - ap.x, g.w - ap.y));
        if (din > EPSF && mlds[tj] > 0.f) {
            float c = ciou2(g.x, g.y, g.z, g.w, g.z - g.x, g.w - g.y, galds[tj],
                            p.x, p.y, p.z, p.w, pat);
            float ov = fmaxf(c, 0.f);
            int gl = gt_labels[b * NMX + tj];
            float s = pd_scores[(size_t)id * NCC + gl];
            float o2 = ov * ov;
            al = s * (o2 * o2 * o2);
            if (ov > 0.f)
                atomicMax((unsigned int*)&pos[NROW + b * NMX + tj], __float_as_uint(ov));
        }
        if (al > 0.f)
            atomicMax((unsigned int*)&pos[b * NMX + tj], __float_as_uint(al));
    }
    tgt[id] = tj; fgm[id] = f; alv[id] = al;
}

// K3: all outputs, fully written (unchanged).
__global__ __launch_bounds__(256) void k3_out(
    const int* __restrict__ gt_labels,
    const float* __restrict__ gt_bboxes,
    const int* __restrict__ tgt, const int* __restrict__ fgm,
    const float* __restrict__ alv, const int* __restrict__ pos,
    float* __restrict__ o_lab, float* __restrict__ o_box, float* __restrict__ o_sc,
    float* __restrict__ o_fg, float* __restrict__ o_ti)
{
    const int id0 = blockIdx.x * 256;
    const int tid = threadIdx.x;
    const int id = id0 + tid;
    const int b = id / NAA;
    const int tj = tgt[id];
    const int f = fgm[id];
    int lab = gt_labels[b * NMX + tj]; lab = lab < 0 ? 0 : lab;
    float4 gb = reinterpret_cast<const float4*>(gt_bboxes)[b * NMX + tj];
    o_lab[id] = (float)lab;
    reinterpret_cast<float4*>(o_box)[id] = gb;
    o_fg[id] = f ? 1.f : 0.f;
    o_ti[id] = (float)tj;
    float val = 0.f;
    if (f) {
        float pa = __uint_as_float((unsigned int)pos[b * NMX + tj]);
        float po = __uint_as_float((unsigned int)pos[NROW + b * NMX + tj]);
        val = (alv[id] * po) / (pa + EPSF);
    }
    __shared__ int   s_lab[256];
    __shared__ float s_val[256];
    s_lab[tid] = lab;
    s_val[tid] = val;
    __syncthreads();
    float4* dst = reinterpret_cast<float4*>(o_sc + (size_t)id0 * NCC);
    const int NV = 256 * NCC / 4;   // 5120 float4s per block
#pragma unroll 4
    for (int i = tid; i < NV; i += 256) {
        int aa = i / (NCC / 4);
        int c0 = (i - aa * (NCC / 4)) * 4;
        int la = s_lab[aa];
        float vv = s_val[aa];
        float4 w;
        w.x = (la == c0 + 0) ? vv : 0.f;
        w.y = (la == c0 + 1) ? vv : 0.f;
        w.z = (la == c0 + 2) ? vv : 0.f;
        w.w = (la == c0 + 3) ? vv : 0.f;
        dst[i] = w;
    }
}

extern "C" void kernel_launch(void* const* d_in, const int* in_sizes, int n_in,
                              void* d_out, int out_size, void* d_ws, size_t ws_size,
                              hipStream_t stream)
{
    const float* pd_scores = (const float*)d_in[0];
    const float* pd_bboxes = (const float*)d_in[1];
    const float* anc       = (const float*)d_in[2];
    // d_in[3] rfields: unused by the reference
    const int*   gt_labels = (const int*)d_in[4];
    const float* gt_bboxes = (const float*)d_in[5];
    const float* mask_gt   = (const float*)d_in[6];

    const size_t nba = (size_t)NBA;
    int* cnt    = (int*)d_ws;                       // NBA
    int* pos    = cnt + nba;                        // 2*NROW
    int* rcount = pos + 2 * NROW;                   // NROW*RPAD
    float* rV   = (float*)(rcount + NROW * RPAD);   // NROW*RCAP
    int* rI     = (int*)(rV + (size_t)NROW * RCAP); // NROW*RCAP
    int* tgt    = rI + (size_t)NROW * RCAP;         // NBA
    int* fgm    = tgt + nba;                        // NBA
    float* alv  = (float*)(fgm + nba);              // NBA

    float* out = (float*)d_out;
    float* o_lab = out;                 // (B,NA)
    float* o_box = out + nba;           // (B,NA,4)
    float* o_sc  = out + nba * 5;       // (B,NA,NC)
    float* o_fg  = out + nba * 85;      // (B,NA)
    float* o_ti  = out + nba * 86;      // (B,NA)

    kz_zero<<<(NROW * RPAD + 255) / 256, 256, 0, stream>>>(rcount);
    kp_scan<<<dim3((NAA + 255) / 256, BB), 256, 0, stream>>>(
        pd_scores, pd_bboxes, anc, gt_labels, gt_bboxes, mask_gt,
        cnt, pos, rcount, rV, rI);
    kb_fin<<<NROW / 4, 256, 0, stream>>>(anc, gt_bboxes, mask_gt,
                                         rcount, rV, rI, cnt);
    k2_resolve<<<dim3((NAA + 255) / 256, BB), 256, 0, stream>>>(
        pd_scores, pd_bboxes, anc, gt_labels, gt_bboxes, mask_gt, cnt,
        tgt, fgm, alv, pos);
    const int nblk = NBA / 256;   // 525, exact
    k3_out<<<nblk, 256, 0, stream>>>(gt_labels, gt_bboxes, tgt, fgm, alv, pos,
                                     o_lab, o_box, o_sc, o_fg, o_ti);
}